// Round 1
// baseline (316.916 us; speedup 1.0000x reference)
//
#include <hip/hip_runtime.h>
#include <hip/hip_bf16.h>

// Problem constants (from reference setup_inputs): B=2, Np=Nc=512, D=P=128.
#define BATCH 2
#define NP 512
#define NC 512
#define DD 128
#define PP 128

typedef __bf16 bf16_t;
typedef __bf16 bf16x8 __attribute__((ext_vector_type(8)));
typedef __bf16 bf16x2 __attribute__((ext_vector_type(2)));
typedef float f32x4 __attribute__((ext_vector_type(4)));

// ---------------- Stage 1: layernorm all rows (p -> f32, c -> bf16) --------
// One 64-lane wave per row of 128. Grid = B*NP (p rows) + B*NC (c rows).
__global__ __launch_bounds__(64) void ln_kernel(
    const float* __restrict__ p, const float* __restrict__ c,
    const float* __restrict__ pw, const float* __restrict__ pb,
    const float* __restrict__ cw, const float* __restrict__ cb,
    float* __restrict__ p_ln, bf16_t* __restrict__ c_bf) {
    int row = blockIdx.x;
    bool isP = row < BATCH * NP;
    int crow = row - BATCH * NP;
    const float* x  = isP ? p + (size_t)row * DD : c + (size_t)crow * DD;
    const float* w  = isP ? pw : cw;
    const float* bs = isP ? pb : cb;
    int t = threadIdx.x;                 // 0..63, 2 contiguous elems each
    float2 v = *(const float2*)&x[2 * t];
    float s  = v.x + v.y;
    float sq = v.x * v.x + v.y * v.y;
    for (int o = 32; o; o >>= 1) {
        s  += __shfl_xor(s, o);
        sq += __shfl_xor(sq, o);
    }
    float mu  = s * (1.0f / 128.0f);
    float var = sq * (1.0f / 128.0f) - mu * mu;
    float rs  = rsqrtf(var + 1e-5f);
    float2 wv = *(const float2*)&w[2 * t];
    float2 bv = *(const float2*)&bs[2 * t];
    float o0 = (v.x - mu) * rs * wv.x + bv.x;
    float o1 = (v.y - mu) * rs * wv.y + bv.y;
    if (isP) {
        float2 o2; o2.x = o0; o2.y = o1;
        *(float2*)&p_ln[(size_t)row * DD + 2 * t] = o2;
    } else {
        bf16x2 o2; o2[0] = (bf16_t)o0; o2[1] = (bf16_t)o1;
        *(bf16x2*)&c_bf[(size_t)crow * DD + 2 * t] = o2;
    }
}

// ---------------- Stage 2: fused interaction, one block per (b, i) ---------
// out[b,i,j,h] = sum_k (W[h,k]*p[i,k]) * c[j,k] + b_out[h], masked.
// Operand swap: mfma(A=W', B=c) puts D rows on h -> each lane's 4 acc regs
// are 4 CONSECUTIVE h values -> float4 stores (vs 64 scalar stores before).
// W' (= W * p[i], bf16) lives entirely in registers (32 VGPR/wave); c frags
// are read straight from L2 (c_bf is 512 KB total). No LDS, no barriers.
// 4 waves: wave w owns h in [w*32, w*32+32), loops all 512 j.
__global__ __launch_bounds__(256, 4) void inter_kernel(
    const float* __restrict__ p_ln, const bf16_t* __restrict__ c_bf,
    const float* __restrict__ W, const float* __restrict__ b_out,
    const int* __restrict__ p_mask,      // bool inputs marshaled as int32
    const int* __restrict__ c_mask,
    float* __restrict__ out) {
    int blk = blockIdx.x;                // 1024 blocks: b*512 + i
    int i = blk & (NP - 1);
    int b = blk >> 9;
    int t = threadIdx.x;
    int lane = t & 63;
    int wave = t >> 6;
    int l16 = lane & 15, q = lane >> 4;

    int pm = p_mask[b * NP + i];

    // Build W' fragments in registers: wf[ht][kt] covers
    // A rows h = wave*32 + ht*16 + l16, k = kt*32 + q*8 .. +7.
    const float* pr = p_ln + ((size_t)(b * NP + i)) * DD;
    bf16x8 wf[2][4];
    #pragma unroll
    for (int ht = 0; ht < 2; ++ht) {
        int h = wave * 32 + ht * 16 + l16;
        const float* wr = W + (size_t)h * DD;
        #pragma unroll
        for (int kt = 0; kt < 4; ++kt) {
            int k = kt * 32 + q * 8;
            float4 w0 = *(const float4*)&wr[k];
            float4 w1 = *(const float4*)&wr[k + 4];
            float4 pv0 = *(const float4*)&pr[k];
            float4 pv1 = *(const float4*)&pr[k + 4];
            bf16x8 f;
            f[0] = (bf16_t)(w0.x * pv0.x); f[1] = (bf16_t)(w0.y * pv0.y);
            f[2] = (bf16_t)(w0.z * pv0.z); f[3] = (bf16_t)(w0.w * pv0.w);
            f[4] = (bf16_t)(w1.x * pv1.x); f[5] = (bf16_t)(w1.y * pv1.y);
            f[6] = (bf16_t)(w1.z * pv1.z); f[7] = (bf16_t)(w1.w * pv1.w);
            wf[ht][kt] = f;
        }
    }

    // bias for this lane's h quads (D row = q*4 + reg -> h contiguous)
    f32x4 bias0 = *(const f32x4*)&b_out[wave * 32 + q * 4];
    f32x4 bias1 = *(const f32x4*)&b_out[wave * 32 + 16 + q * 4];

    const bf16_t* cbb = c_bf + (size_t)b * NC * DD;
    const int* cmb = c_mask + b * NC;
    size_t outbase = (((size_t)b * NP + i) * NC) * PP;

    #pragma unroll 2
    for (int jt = 0; jt < NC / 16; ++jt) {
        int j = jt * 16 + l16;
        // B fragments: col j = l16, k = kt*32 + q*8 (16 B contiguous loads, L2-hot)
        bf16x8 cf[4];
        #pragma unroll
        for (int kt = 0; kt < 4; ++kt)
            cf[kt] = *(const bf16x8*)&cbb[(size_t)j * DD + kt * 32 + q * 8];
        f32x4 acc0 = {0.f, 0.f, 0.f, 0.f};
        f32x4 acc1 = {0.f, 0.f, 0.f, 0.f};
        #pragma unroll
        for (int kt = 0; kt < 4; ++kt) {
            acc0 = __builtin_amdgcn_mfma_f32_16x16x32_bf16(wf[0][kt], cf[kt], acc0, 0, 0, 0);
            acc1 = __builtin_amdgcn_mfma_f32_16x16x32_bf16(wf[1][kt], cf[kt], acc1, 0, 0, 0);
        }
        float scale = (pm != 0 && cmb[j] != 0) ? 1.0f : 0.0f;
        // lane writes h = wave*32 (+16) + q*4 .. +3 for row j: two float4s
        float* orow = out + outbase + (size_t)j * PP + wave * 32 + q * 4;
        *(f32x4*)&orow[0]  = (acc0 + bias0) * scale;
        *(f32x4*)&orow[16] = (acc1 + bias1) * scale;
    }

    // mask plane for this (b,i): 512 floats
    size_t mbase = (size_t)BATCH * NP * NC * PP;
    for (int jj = t; jj < NC; jj += 256) {
        out[mbase + ((size_t)b * NP + i) * NC + jj] =
            (pm != 0 && cmb[jj] != 0) ? 1.0f : 0.0f;
    }
}

extern "C" void kernel_launch(void* const* d_in, const int* in_sizes, int n_in,
                              void* d_out, int out_size, void* d_ws, size_t ws_size,
                              hipStream_t stream) {
    const float* p_embed = (const float*)d_in[0];
    const float* c_embed = (const float*)d_in[1];
    const int* p_mask = (const int*)d_in[2];   // bool -> int32 per harness rule
    const int* c_mask = (const int*)d_in[3];
    const float* ln_p_w = (const float*)d_in[4];
    const float* ln_p_b = (const float*)d_in[5];
    const float* ln_c_w = (const float*)d_in[6];
    const float* ln_c_b = (const float*)d_in[7];
    const float* W_out  = (const float*)d_in[8];
    const float* b_out  = (const float*)d_in[9];
    float* out = (float*)d_out;

    // workspace: p_ln f32 [2*512*128] | c_bf bf16 [2*512*128]
    float* p_ln = (float*)d_ws;
    bf16_t* c_bf = (bf16_t*)(p_ln + (size_t)BATCH * NP * DD);

    ln_kernel<<<BATCH * (NP + NC), 64, 0, stream>>>(
        p_embed, c_embed, ln_p_w, ln_p_b, ln_c_w, ln_c_b, p_ln, c_bf);
    inter_kernel<<<BATCH * NP, 256, 0, stream>>>(
        p_ln, c_bf, W_out, b_out, p_mask, c_mask, out);
}

// Round 3
// 302.142 us; speedup vs baseline: 1.0489x; 1.0489x over previous
//
#include <hip/hip_runtime.h>
#include <hip/hip_bf16.h>

// Problem constants (from reference setup_inputs): B=2, Np=Nc=512, D=P=128.
#define BATCH 2
#define NP 512
#define NC 512
#define DD 128
#define PP 128

typedef __bf16 bf16_t;
typedef __bf16 bf16x8 __attribute__((ext_vector_type(8)));
typedef __bf16 bf16x2 __attribute__((ext_vector_type(2)));
typedef float f32x4 __attribute__((ext_vector_type(4)));

// ---------------- Stage 1: layernorm all rows (p -> f32, c -> bf16) --------
// One 64-lane wave per row of 128. Grid = B*NP (p rows) + B*NC (c rows).
__global__ __launch_bounds__(64) void ln_kernel(
    const float* __restrict__ p, const float* __restrict__ c,
    const float* __restrict__ pw, const float* __restrict__ pb,
    const float* __restrict__ cw, const float* __restrict__ cb,
    float* __restrict__ p_ln, bf16_t* __restrict__ c_bf) {
    int row = blockIdx.x;
    bool isP = row < BATCH * NP;
    int crow = row - BATCH * NP;
    const float* x  = isP ? p + (size_t)row * DD : c + (size_t)crow * DD;
    const float* w  = isP ? pw : cw;
    const float* bs = isP ? pb : cb;
    int t = threadIdx.x;                 // 0..63, 2 contiguous elems each
    float2 v = *(const float2*)&x[2 * t];
    float s  = v.x + v.y;
    float sq = v.x * v.x + v.y * v.y;
    for (int o = 32; o; o >>= 1) {
        s  += __shfl_xor(s, o);
        sq += __shfl_xor(sq, o);
    }
    float mu  = s * (1.0f / 128.0f);
    float var = sq * (1.0f / 128.0f) - mu * mu;
    float rs  = rsqrtf(var + 1e-5f);
    float2 wv = *(const float2*)&w[2 * t];
    float2 bv = *(const float2*)&bs[2 * t];
    float o0 = (v.x - mu) * rs * wv.x + bv.x;
    float o1 = (v.y - mu) * rs * wv.y + bv.y;
    if (isP) {
        float2 o2; o2.x = o0; o2.y = o1;
        *(float2*)&p_ln[(size_t)row * DD + 2 * t] = o2;
    } else {
        bf16x2 o2; o2[0] = (bf16_t)o0; o2[1] = (bf16_t)o1;
        *(bf16x2*)&c_bf[(size_t)crow * DD + 2 * t] = o2;
    }
}

// ---------------- Stage 2: fused interaction ------------------------------
// out[b,i,j,h] = sum_k (W[h,k]*p[i,k]) * c[j,k] + b_out[h], masked.
// One block per (b, i, j-quarter of 128). mfma(A=W', B=c) -> D rows on h:
// each lane's 4 acc regs = 4 consecutive h -> float4 stores.
// W' = W*p[i] lives in registers (32 VGPR/wave). c tile staged in LDS ONCE
// before any store issues, so the hot loop is ds_read (lgkmcnt) + MFMA +
// fire-and-forget stores (vmcnt, never waited) -- no vmcnt false dependency
// between loads and stores (the round-1 regression).
__global__ __launch_bounds__(256, 4) void inter_kernel(
    const float* __restrict__ p_ln, const bf16_t* __restrict__ c_bf,
    const float* __restrict__ W, const float* __restrict__ b_out,
    const int* __restrict__ p_mask,      // bool inputs marshaled as int32
    const int* __restrict__ c_mask,
    float* __restrict__ out) {
    // +8 bf16 pad (16 B) per row: row stride 272 B -> 4-bank stagger,
    // 2-way aliasing on ds_read_b128 (free per m136)
    __shared__ bf16_t As[128][136];

    int blk = blockIdx.x;            // 4096 blocks
    int jq = blk & 3;                // j-quarter
    int i  = (blk >> 2) & (NP - 1);
    int b  = blk >> 11;
    int j0 = jq * 128;

    int t = threadIdx.x;
    int lane = t & 63;
    int wave = t >> 6;
    int l16 = lane & 15, q = lane >> 4;

    // ---- stage c tile: 128 rows x 128 bf16 (32 KB), reg-staged ----
    const bf16_t* cbb = c_bf + ((size_t)(b * NC + j0)) * DD;
    {
        int col = (t & 15) * 8;      // 16 B per thread per row
        int rg = t >> 4;             // 16 rows per pass
        #pragma unroll
        for (int pass = 0; pass < 8; ++pass) {
            int r = pass * 16 + rg;
            *(bf16x8*)&As[r][col] = *(const bf16x8*)&cbb[(size_t)r * DD + col];
        }
    }

    // ---- masks -> 8 per-lane scale registers (no global loads in loop) ----
    int pm = p_mask[b * NP + i];
    const int* cmb = c_mask + b * NC + j0;
    float sc[8];
    #pragma unroll
    for (int jt = 0; jt < 8; ++jt)
        sc[jt] = (pm != 0 && cmb[jt * 16 + l16] != 0) ? 1.0f : 0.0f;

    // ---- W' fragments in registers: rows h = wave*32 + ht*16 + l16 ----
    const float* pr = p_ln + ((size_t)(b * NP + i)) * DD;
    bf16x8 wf[2][4];
    #pragma unroll
    for (int ht = 0; ht < 2; ++ht) {
        int h = wave * 32 + ht * 16 + l16;
        const float* wr = W + (size_t)h * DD;
        #pragma unroll
        for (int kt = 0; kt < 4; ++kt) {
            int k = kt * 32 + q * 8;
            float4 w0 = *(const float4*)&wr[k];
            float4 w1 = *(const float4*)&wr[k + 4];
            float4 pv0 = *(const float4*)&pr[k];
            float4 pv1 = *(const float4*)&pr[k + 4];
            bf16x8 f;
            f[0] = (bf16_t)(w0.x * pv0.x); f[1] = (bf16_t)(w0.y * pv0.y);
            f[2] = (bf16_t)(w0.z * pv0.z); f[3] = (bf16_t)(w0.w * pv0.w);
            f[4] = (bf16_t)(w1.x * pv1.x); f[5] = (bf16_t)(w1.y * pv1.y);
            f[6] = (bf16_t)(w1.z * pv1.z); f[7] = (bf16_t)(w1.w * pv1.w);
            wf[ht][kt] = f;
        }
    }

    // bias for this lane's h quads (D row = q*4 + reg -> h contiguous)
    f32x4 bias0 = *(const f32x4*)&b_out[wave * 32 + q * 4];
    f32x4 bias1 = *(const f32x4*)&b_out[wave * 32 + 16 + q * 4];

    __syncthreads();

    size_t outbase = (((size_t)b * NP + i) * NC + j0) * PP;
    #pragma unroll 2
    for (int jt = 0; jt < 8; ++jt) {
        int jr = jt * 16 + l16;
        // B fragments from LDS: col j = l16-row, k = kt*32 + q*8
        bf16x8 cf[4];
        #pragma unroll
        for (int kt = 0; kt < 4; ++kt)
            cf[kt] = *(const bf16x8*)&As[jr][kt * 32 + q * 8];
        f32x4 acc0 = {0.f, 0.f, 0.f, 0.f};
        f32x4 acc1 = {0.f, 0.f, 0.f, 0.f};
        #pragma unroll
        for (int kt = 0; kt < 4; ++kt) {
            acc0 = __builtin_amdgcn_mfma_f32_16x16x32_bf16(wf[0][kt], cf[kt], acc0, 0, 0, 0);
            acc1 = __builtin_amdgcn_mfma_f32_16x16x32_bf16(wf[1][kt], cf[kt], acc1, 0, 0, 0);
        }
        // lane writes h = wave*32 (+16) + q*4 .. +3 for row j0+jr: two float4s
        float* orow = out + outbase + (size_t)jr * PP + wave * 32 + q * 4;
        *(f32x4*)&orow[0]  = (acc0 + bias0) * sc[jt];
        *(f32x4*)&orow[16] = (acc1 + bias1) * sc[jt];
    }

    // mask plane for this (b,i,jq): 128 floats
    if (t < 128) {
        size_t mbase = (size_t)BATCH * NP * NC * PP;
        out[mbase + ((size_t)b * NP + i) * NC + j0 + t] =
            (pm != 0 && cmb[t] != 0) ? 1.0f : 0.0f;
    }
}

extern "C" void kernel_launch(void* const* d_in, const int* in_sizes, int n_in,
                              void* d_out, int out_size, void* d_ws, size_t ws_size,
                              hipStream_t stream) {
    const float* p_embed = (const float*)d_in[0];
    const float* c_embed = (const float*)d_in[1];
    const int* p_mask = (const int*)d_in[2];   // bool -> int32 per harness rule
    const int* c_mask = (const int*)d_in[3];
    const float* ln_p_w = (const float*)d_in[4];
    const float* ln_p_b = (const float*)d_in[5];
    const float* ln_c_w = (const float*)d_in[6];
    const float* ln_c_b = (const float*)d_in[7];
    const float* W_out  = (const float*)d_in[8];
    const float* b_out  = (const float*)d_in[9];
    float* out = (float*)d_out;

    // workspace: p_ln f32 [2*512*128] | c_bf bf16 [2*512*128]
    float* p_ln = (float*)d_ws;
    bf16_t* c_bf = (bf16_t*)(p_ln + (size_t)BATCH * NP * DD);

    ln_kernel<<<BATCH * (NP + NC), 64, 0, stream>>>(
        p_embed, c_embed, ln_p_w, ln_p_b, ln_c_w, ln_c_b, p_ln, c_bf);
    inter_kernel<<<BATCH * NP * (NC / 128), 256, 0, stream>>>(
        p_ln, c_bf, W_out, b_out, p_mask, c_mask, out);
}

// Round 4
// 293.430 us; speedup vs baseline: 1.0800x; 1.0297x over previous
//
#include <hip/hip_runtime.h>
#include <hip/hip_bf16.h>

// Problem constants (from reference setup_inputs): B=2, Np=Nc=512, D=P=128.
#define BATCH 2
#define NP 512
#define NC 512
#define DD 128
#define PP 128

typedef __bf16 bf16_t;
typedef __bf16 bf16x8 __attribute__((ext_vector_type(8)));
typedef __bf16 bf16x2 __attribute__((ext_vector_type(2)));
typedef float f32x4 __attribute__((ext_vector_type(4)));

// ---------------- Stage 1: layernorm all rows (p -> f32, c -> bf16) --------
// One 64-lane wave per row of 128. Grid = B*NP (p rows) + B*NC (c rows).
__global__ __launch_bounds__(64) void ln_kernel(
    const float* __restrict__ p, const float* __restrict__ c,
    const float* __restrict__ pw, const float* __restrict__ pb,
    const float* __restrict__ cw, const float* __restrict__ cb,
    float* __restrict__ p_ln, bf16_t* __restrict__ c_bf) {
    int row = blockIdx.x;
    bool isP = row < BATCH * NP;
    int crow = row - BATCH * NP;
    const float* x  = isP ? p + (size_t)row * DD : c + (size_t)crow * DD;
    const float* w  = isP ? pw : cw;
    const float* bs = isP ? pb : cb;
    int t = threadIdx.x;                 // 0..63, 2 contiguous elems each
    float2 v = *(const float2*)&x[2 * t];
    float s  = v.x + v.y;
    float sq = v.x * v.x + v.y * v.y;
    for (int o = 32; o; o >>= 1) {
        s  += __shfl_xor(s, o);
        sq += __shfl_xor(sq, o);
    }
    float mu  = s * (1.0f / 128.0f);
    float var = sq * (1.0f / 128.0f) - mu * mu;
    float rs  = rsqrtf(var + 1e-5f);
    float2 wv = *(const float2*)&w[2 * t];
    float2 bv = *(const float2*)&bs[2 * t];
    float o0 = (v.x - mu) * rs * wv.x + bv.x;
    float o1 = (v.y - mu) * rs * wv.y + bv.y;
    if (isP) {
        float2 o2; o2.x = o0; o2.y = o1;
        *(float2*)&p_ln[(size_t)row * DD + 2 * t] = o2;
    } else {
        bf16x2 o2; o2[0] = (bf16_t)o0; o2[1] = (bf16_t)o1;
        *(bf16x2*)&c_bf[(size_t)crow * DD + 2 * t] = o2;
    }
}

// ---------------- Stage 2: fused interaction ------------------------------
// out[b,i,j,h] = sum_k (W[h,k]*p[i,k]) * c[j,k] + b_out[h], masked.
// Identical to round 3 EXCEPT the epilogue: per-wave ds_bpermute repack so
// that every global_store_dwordx4 covers FULL 128-B-aligned lines
// (8 rows x 128 B per instruction) instead of 16 rows x 64 B half-lines.
// Theory under test: partial-line stores trigger L2 write-allocate RMW
// (~268 MB of extra HBM fetch) -- the common factor in r0/r1/r3 all
// sitting at ~3x the write-BW floor.
__global__ __launch_bounds__(256, 4) void inter_kernel(
    const float* __restrict__ p_ln, const bf16_t* __restrict__ c_bf,
    const float* __restrict__ W, const float* __restrict__ b_out,
    const int* __restrict__ p_mask,      // bool inputs marshaled as int32
    const int* __restrict__ c_mask,
    float* __restrict__ out) {
    // +8 bf16 pad (16 B) per row: 2-way bank aliasing on ds_read_b128 (free)
    __shared__ bf16_t As[128][136];

    int blk = blockIdx.x;            // 4096 blocks
    int jq = blk & 3;                // j-quarter
    int i  = (blk >> 2) & (NP - 1);
    int b  = blk >> 11;
    int j0 = jq * 128;

    int t = threadIdx.x;
    int lane = t & 63;
    int wave = t >> 6;
    int l16 = lane & 15, q = lane >> 4;

    // ---- stage c tile: 128 rows x 128 bf16 (32 KB), reg-staged ----
    const bf16_t* cbb = c_bf + ((size_t)(b * NC + j0)) * DD;
    {
        int col = (t & 15) * 8;      // 16 B per thread per row
        int rg = t >> 4;             // 16 rows per pass
        #pragma unroll
        for (int pass = 0; pass < 8; ++pass) {
            int r = pass * 16 + rg;
            *(bf16x8*)&As[r][col] = *(const bf16x8*)&cbb[(size_t)r * DD + col];
        }
    }

    // ---- masks -> 8 per-lane scale registers (indexed by SOURCE row l16) --
    int pm = p_mask[b * NP + i];
    const int* cmb = c_mask + b * NC + j0;
    float sc[8];
    #pragma unroll
    for (int jt = 0; jt < 8; ++jt)
        sc[jt] = (pm != 0 && cmb[jt * 16 + l16] != 0) ? 1.0f : 0.0f;

    // ---- W' fragments in registers: rows h = wave*32 + ht*16 + l16 ----
    const float* pr = p_ln + ((size_t)(b * NP + i)) * DD;
    bf16x8 wf[2][4];
    #pragma unroll
    for (int ht = 0; ht < 2; ++ht) {
        int h = wave * 32 + ht * 16 + l16;
        const float* wr = W + (size_t)h * DD;
        #pragma unroll
        for (int kt = 0; kt < 4; ++kt) {
            int k = kt * 32 + q * 8;
            float4 w0 = *(const float4*)&wr[k];
            float4 w1 = *(const float4*)&wr[k + 4];
            float4 pv0 = *(const float4*)&pr[k];
            float4 pv1 = *(const float4*)&pr[k + 4];
            bf16x8 f;
            f[0] = (bf16_t)(w0.x * pv0.x); f[1] = (bf16_t)(w0.y * pv0.y);
            f[2] = (bf16_t)(w0.z * pv0.z); f[3] = (bf16_t)(w0.w * pv0.w);
            f[4] = (bf16_t)(w1.x * pv1.x); f[5] = (bf16_t)(w1.y * pv1.y);
            f[6] = (bf16_t)(w1.z * pv1.z); f[7] = (bf16_t)(w1.w * pv1.w);
            wf[ht][kt] = f;
        }
    }

    // bias for this lane's h quads (source layout: D row = q*4 + reg)
    f32x4 bias0 = *(const f32x4*)&b_out[wave * 32 + q * 4];
    f32x4 bias1 = *(const f32x4*)&b_out[wave * 32 + 16 + q * 4];

    // ---- epilogue repack constants (per-lane, hoisted) ----
    // Target layout: lane T stores row jt*16 + (T>>3), 16-B chunk c = T&7 of
    // this wave's 128-B h-strip. Source of that chunk: lane S = ((c&3)<<4) |
    // row_local, register acc0 if c<4 else acc1. ds_bpermute idx = S*4.
    int cc   = lane & 7;                       // chunk within 128-B line
    int idxA = ((((cc & 3) << 4) | (lane >> 3))) << 2;       // rows 0..7
    int idxB = idxA + 32;                                     // rows 8..15 (S+8)

    __syncthreads();

    size_t outbase = (((size_t)b * NP + i) * NC + j0) * PP;
    #pragma unroll 2
    for (int jt = 0; jt < 8; ++jt) {
        int jr = jt * 16 + l16;
        // B fragments from LDS: col j = l16-row, k = kt*32 + q*8
        bf16x8 cf[4];
        #pragma unroll
        for (int kt = 0; kt < 4; ++kt)
            cf[kt] = *(const bf16x8*)&As[jr][kt * 32 + q * 8];
        f32x4 acc0 = {0.f, 0.f, 0.f, 0.f};
        f32x4 acc1 = {0.f, 0.f, 0.f, 0.f};
        #pragma unroll
        for (int kt = 0; kt < 4; ++kt) {
            acc0 = __builtin_amdgcn_mfma_f32_16x16x32_bf16(wf[0][kt], cf[kt], acc0, 0, 0, 0);
            acc1 = __builtin_amdgcn_mfma_f32_16x16x32_bf16(wf[1][kt], cf[kt], acc1, 0, 0, 0);
        }
        // bias + mask in SOURCE layout (row = l16)
        f32x4 a0 = (acc0 + bias0) * sc[jt];
        f32x4 a1 = (acc1 + bias1) * sc[jt];

        // ---- repack: full-line stores. vA/vB[r] = float (h-off cc*4+r) of
        // target row; pull both candidate regs, select by cc ----
        f32x4 vA, vB;
        #pragma unroll
        for (int r = 0; r < 4; ++r) {
            int s0A = __builtin_amdgcn_ds_bpermute(idxA, __float_as_int(a0[r]));
            int s1A = __builtin_amdgcn_ds_bpermute(idxA, __float_as_int(a1[r]));
            vA[r] = __int_as_float(cc < 4 ? s0A : s1A);
            int s0B = __builtin_amdgcn_ds_bpermute(idxB, __float_as_int(a0[r]));
            int s1B = __builtin_amdgcn_ds_bpermute(idxB, __float_as_int(a1[r]));
            vB[r] = __int_as_float(cc < 4 ? s0B : s1B);
        }
        // one instruction = 8 rows x one full 128-B line each
        int rowA = jt * 16 + (lane >> 3);
        int rowB = rowA + 8;
        *(f32x4*)(out + outbase + (size_t)rowA * PP + wave * 32 + cc * 4) = vA;
        *(f32x4*)(out + outbase + (size_t)rowB * PP + wave * 32 + cc * 4) = vB;
    }

    // mask plane for this (b,i,jq): 128 floats
    if (t < 128) {
        size_t mbase = (size_t)BATCH * NP * NC * PP;
        out[mbase + ((size_t)b * NP + i) * NC + j0 + t] =
            (pm != 0 && cmb[t] != 0) ? 1.0f : 0.0f;
    }
}

extern "C" void kernel_launch(void* const* d_in, const int* in_sizes, int n_in,
                              void* d_out, int out_size, void* d_ws, size_t ws_size,
                              hipStream_t stream) {
    const float* p_embed = (const float*)d_in[0];
    const float* c_embed = (const float*)d_in[1];
    const int* p_mask = (const int*)d_in[2];   // bool -> int32 per harness rule
    const int* c_mask = (const int*)d_in[3];
    const float* ln_p_w = (const float*)d_in[4];
    const float* ln_p_b = (const float*)d_in[5];
    const float* ln_c_w = (const float*)d_in[6];
    const float* ln_c_b = (const float*)d_in[7];
    const float* W_out  = (const float*)d_in[8];
    const float* b_out  = (const float*)d_in[9];
    float* out = (float*)d_out;

    // workspace: p_ln f32 [2*512*128] | c_bf bf16 [2*512*128]
    float* p_ln = (float*)d_ws;
    bf16_t* c_bf = (bf16_t*)(p_ln + (size_t)BATCH * NP * DD);

    ln_kernel<<<BATCH * (NP + NC), 64, 0, stream>>>(
        p_embed, c_embed, ln_p_w, ln_p_b, ln_c_w, ln_c_b, p_ln, c_bf);
    inter_kernel<<<BATCH * NP * (NC / 128), 256, 0, stream>>>(
        p_ln, c_bf, W_out, b_out, p_mask, c_mask, out);
}

// Round 5
// 284.362 us; speedup vs baseline: 1.1145x; 1.0319x over previous
//
#include <hip/hip_runtime.h>
#include <hip/hip_bf16.h>

// Problem constants (from reference setup_inputs): B=2, Np=Nc=512, D=P=128.
#define BATCH 2
#define NP 512
#define NC 512
#define DD 128
#define PP 128
#define ITILE 8

typedef __bf16 bf16_t;
typedef __bf16 bf16x8 __attribute__((ext_vector_type(8)));
typedef __bf16 bf16x2 __attribute__((ext_vector_type(2)));
typedef float f32x4 __attribute__((ext_vector_type(4)));

// ---------------- Stage 1: layernorm all rows (p -> f32, c -> bf16) --------
// One 64-lane wave per row of 128. Grid = B*NP (p rows) + B*NC (c rows).
__global__ __launch_bounds__(64) void ln_kernel(
    const float* __restrict__ p, const float* __restrict__ c,
    const float* __restrict__ pw, const float* __restrict__ pb,
    const float* __restrict__ cw, const float* __restrict__ cb,
    float* __restrict__ p_ln, bf16_t* __restrict__ c_bf) {
    int row = blockIdx.x;
    bool isP = row < BATCH * NP;
    int crow = row - BATCH * NP;
    const float* x  = isP ? p + (size_t)row * DD : c + (size_t)crow * DD;
    const float* w  = isP ? pw : cw;
    const float* bs = isP ? pb : cb;
    int t = threadIdx.x;                 // 0..63, 2 contiguous elems each
    float2 v = *(const float2*)&x[2 * t];
    float s  = v.x + v.y;
    float sq = v.x * v.x + v.y * v.y;
    for (int o = 32; o; o >>= 1) {
        s  += __shfl_xor(s, o);
        sq += __shfl_xor(sq, o);
    }
    float mu  = s * (1.0f / 128.0f);
    float var = sq * (1.0f / 128.0f) - mu * mu;
    float rs  = rsqrtf(var + 1e-5f);
    float2 wv = *(const float2*)&w[2 * t];
    float2 bv = *(const float2*)&bs[2 * t];
    float o0 = (v.x - mu) * rs * wv.x + bv.x;
    float o1 = (v.y - mu) * rs * wv.y + bv.y;
    if (isP) {
        float2 o2; o2.x = o0; o2.y = o1;
        *(float2*)&p_ln[(size_t)row * DD + 2 * t] = o2;
    } else {
        bf16x2 o2; o2[0] = (bf16_t)o0; o2[1] = (bf16_t)o1;
        *(bf16x2*)&c_bf[(size_t)crow * DD + 2 * t] = o2;
    }
}

// ---------------- Stage 2: fused interaction ------------------------------
// out[b,i,j,h] = sum_k (W[h,k]*p[i,k]) * c[j,k] + b_out[h], masked.
// Theory under test: the 268 MB write stream thrashes L2, so per-block
// operand re-reads (~400 MB in r4, mostly W f32 64KB x 4096 blocks) come
// from L3/HBM and serialize against the writes (~2.5x gap, structure-
// independent across r0-r4). Fix: tile 8 i-rows per block + hold W in
// registers per wave (read ONCE, reused for all 8 i) -> total reads drop
// to ~70 MB. All global reads finish before the first store. Stores keep
// the r4 full-line repack.
__global__ __launch_bounds__(256, 2) void inter_kernel(
    const float* __restrict__ p_ln, const bf16_t* __restrict__ c_bf,
    const float* __restrict__ W, const float* __restrict__ b_out,
    const int* __restrict__ p_mask,      // bool inputs marshaled as int32
    const int* __restrict__ c_mask,
    float* __restrict__ out) {
    // +8 bf16 pad (16 B) per row: 2-way bank aliasing on ds_read_b128 (free)
    __shared__ bf16_t Cs[128][136];
    __shared__ float  Ps[ITILE][DD];

    int blk = blockIdx.x;            // 512 blocks: b*256 + it*4 + jq
    int jq = blk & 3;
    int it = (blk >> 2) & 63;
    int b  = blk >> 8;
    int i0 = it * ITILE;
    int j0 = jq * 128;

    int t = threadIdx.x;
    int lane = t & 63;
    int wave = t >> 6;
    int l16 = lane & 15, q = lane >> 4;

    // ---- stage c quarter: 128 rows x 128 bf16 (32 KB) ----
    const bf16_t* cbb = c_bf + ((size_t)(b * NC + j0)) * DD;
    {
        int col = (t & 15) * 8;      // 16 B per thread per row
        int rg = t >> 4;             // 16 rows per pass
        #pragma unroll
        for (int pass = 0; pass < 8; ++pass) {
            int r = pass * 16 + rg;
            *(bf16x8*)&Cs[r][col] = *(const bf16x8*)&cbb[(size_t)r * DD + col];
        }
    }
    // ---- stage 8 p rows (f32, 4 KB) ----
    {
        int pr_ = t >> 5;            // 0..7
        int pc  = (t & 31) * 4;
        *(f32x4*)&Ps[pr_][pc] =
            *(const f32x4*)&p_ln[((size_t)(b * NP + i0 + pr_)) * DD + pc];
    }

    // ---- W rows for this wave -> REGISTERS (f32), read once, 8x reuse ----
    // lane covers rows h = wave*32 + ht*16 + l16, cols kt*32 + q*8 .. +7
    f32x4 wreg[2][4][2];
    #pragma unroll
    for (int ht = 0; ht < 2; ++ht) {
        const float* wr = W + (size_t)(wave * 32 + ht * 16 + l16) * DD;
        #pragma unroll
        for (int kt = 0; kt < 4; ++kt) {
            int k = kt * 32 + q * 8;
            wreg[ht][kt][0] = *(const f32x4*)&wr[k];
            wreg[ht][kt][1] = *(const f32x4*)&wr[k + 4];
        }
    }

    // ---- masks -> registers (no global reads after sync except stores) ----
    int pmv[ITILE];
    #pragma unroll
    for (int ii = 0; ii < ITILE; ++ii)
        pmv[ii] = p_mask[b * NP + i0 + ii];
    const int* cmb = c_mask + b * NC + j0;
    float sc[8];
    #pragma unroll
    for (int jt = 0; jt < 8; ++jt)
        sc[jt] = (cmb[jt * 16 + l16] != 0) ? 1.0f : 0.0f;
    int4 cm4 = *(const int4*)&cmb[(t & 31) * 4];

    // bias regs (source layout: D row = q*4 + reg -> h contiguous)
    f32x4 bias0 = *(const f32x4*)&b_out[wave * 32 + q * 4];
    f32x4 bias1 = *(const f32x4*)&b_out[wave * 32 + 16 + q * 4];

    // ---- epilogue repack constants (full-128B-line stores, as r4) ----
    int cc   = lane & 7;                       // chunk within 128-B line
    int idxA = ((((cc & 3) << 4) | (lane >> 3))) << 2;       // rows 0..7
    int idxB = idxA + 32;                                     // rows 8..15

    __syncthreads();

    // ---- mask plane: 8 rows x 128 cols, one f32x4 per thread ----
    {
        int mr = t >> 5;
        int mc = (t & 31) * 4;
        size_t mbase = (size_t)BATCH * NP * NC * PP;
        f32x4 mv;
        mv[0] = (pmv[mr] != 0 && cm4.x != 0) ? 1.0f : 0.0f;
        mv[1] = (pmv[mr] != 0 && cm4.y != 0) ? 1.0f : 0.0f;
        mv[2] = (pmv[mr] != 0 && cm4.z != 0) ? 1.0f : 0.0f;
        mv[3] = (pmv[mr] != 0 && cm4.w != 0) ? 1.0f : 0.0f;
        *(f32x4*)&out[mbase + ((size_t)b * NP + i0 + mr) * NC + j0 + mc] = mv;
    }

    // ---- i-loop: rebuild W' = bf16(W * p_i) per i (identical numerics to
    // r4: each MFMA term = bf16(c) * bf16(W*p), single rounding each) ----
    #pragma unroll 1
    for (int ii = 0; ii < ITILE; ++ii) {
        bf16x8 wf[2][4];
        #pragma unroll
        for (int kt = 0; kt < 4; ++kt) {
            int k = kt * 32 + q * 8;
            f32x4 pv0 = *(const f32x4*)&Ps[ii][k];
            f32x4 pv1 = *(const f32x4*)&Ps[ii][k + 4];
            #pragma unroll
            for (int ht = 0; ht < 2; ++ht) {
                f32x4 w0 = wreg[ht][kt][0];
                f32x4 w1 = wreg[ht][kt][1];
                bf16x8 f;
                f[0] = (bf16_t)(w0[0] * pv0[0]); f[1] = (bf16_t)(w0[1] * pv0[1]);
                f[2] = (bf16_t)(w0[2] * pv0[2]); f[3] = (bf16_t)(w0[3] * pv0[3]);
                f[4] = (bf16_t)(w1[0] * pv1[0]); f[5] = (bf16_t)(w1[1] * pv1[1]);
                f[6] = (bf16_t)(w1[2] * pv1[2]); f[7] = (bf16_t)(w1[3] * pv1[3]);
                wf[ht][kt] = f;
            }
        }
        float pmf = (pmv[ii] != 0) ? 1.0f : 0.0f;
        size_t outbase = (((size_t)b * NP + i0 + ii) * NC + j0) * PP;
        #pragma unroll 2
        for (int jt = 0; jt < 8; ++jt) {
            int jr = jt * 16 + l16;
            bf16x8 cf[4];
            #pragma unroll
            for (int kt = 0; kt < 4; ++kt)
                cf[kt] = *(const bf16x8*)&Cs[jr][kt * 32 + q * 8];
            f32x4 acc0 = {0.f, 0.f, 0.f, 0.f};
            f32x4 acc1 = {0.f, 0.f, 0.f, 0.f};
            #pragma unroll
            for (int kt = 0; kt < 4; ++kt) {
                acc0 = __builtin_amdgcn_mfma_f32_16x16x32_bf16(wf[0][kt], cf[kt], acc0, 0, 0, 0);
                acc1 = __builtin_amdgcn_mfma_f32_16x16x32_bf16(wf[1][kt], cf[kt], acc1, 0, 0, 0);
            }
            float s = sc[jt] * pmf;
            f32x4 a0 = (acc0 + bias0) * s;
            f32x4 a1 = (acc1 + bias1) * s;

            // repack to full-line stores: lane T -> row jt*16 + (T>>3),
            // 16-B chunk cc of this wave's 128-B h-strip
            f32x4 vA, vB;
            #pragma unroll
            for (int r = 0; r < 4; ++r) {
                int s0A = __builtin_amdgcn_ds_bpermute(idxA, __float_as_int(a0[r]));
                int s1A = __builtin_amdgcn_ds_bpermute(idxA, __float_as_int(a1[r]));
                vA[r] = __int_as_float(cc < 4 ? s0A : s1A);
                int s0B = __builtin_amdgcn_ds_bpermute(idxB, __float_as_int(a0[r]));
                int s1B = __builtin_amdgcn_ds_bpermute(idxB, __float_as_int(a1[r]));
                vB[r] = __int_as_float(cc < 4 ? s0B : s1B);
            }
            int rowA = jt * 16 + (lane >> 3);
            int rowB = rowA + 8;
            *(f32x4*)(out + outbase + (size_t)rowA * PP + wave * 32 + cc * 4) = vA;
            *(f32x4*)(out + outbase + (size_t)rowB * PP + wave * 32 + cc * 4) = vB;
        }
    }
}

extern "C" void kernel_launch(void* const* d_in, const int* in_sizes, int n_in,
                              void* d_out, int out_size, void* d_ws, size_t ws_size,
                              hipStream_t stream) {
    const float* p_embed = (const float*)d_in[0];
    const float* c_embed = (const float*)d_in[1];
    const int* p_mask = (const int*)d_in[2];   // bool -> int32 per harness rule
    const int* c_mask = (const int*)d_in[3];
    const float* ln_p_w = (const float*)d_in[4];
    const float* ln_p_b = (const float*)d_in[5];
    const float* ln_c_w = (const float*)d_in[6];
    const float* ln_c_b = (const float*)d_in[7];
    const float* W_out  = (const float*)d_in[8];
    const float* b_out  = (const float*)d_in[9];
    float* out = (float*)d_out;

    // workspace: p_ln f32 [2*512*128] | c_bf bf16 [2*512*128]
    float* p_ln = (float*)d_ws;
    bf16_t* c_bf = (bf16_t*)(p_ln + (size_t)BATCH * NP * DD);

    ln_kernel<<<BATCH * (NP + NC), 64, 0, stream>>>(
        p_embed, c_embed, ln_p_w, ln_p_b, ln_c_w, ln_c_b, p_ln, c_bf);
    // 512 blocks = B * (NP/ITILE) * (NC/128); exactly 2 blocks/CU, one round
    inter_kernel<<<BATCH * (NP / ITILE) * (NC / 128), 256, 0, stream>>>(
        p_ln, c_bf, W_out, b_out, p_mask, c_mask, out);
}